// Round 6
// baseline (652.760 us; speedup 1.0000x reference)
//
#include <hip/hip_runtime.h>
#include <hip/hip_bf16.h>
#include <math.h>

typedef __bf16 bf16;
typedef __bf16 bf16x4 __attribute__((ext_vector_type(4)));
typedef __bf16 bf16x8 __attribute__((ext_vector_type(8)));
typedef float f32x4 __attribute__((ext_vector_type(4)));

typedef const __attribute__((address_space(1))) char gchar;
typedef __attribute__((address_space(3))) char lchar;

// Problem constants (B=32, H=W=64, C=192, WS=8, SHIFT=4, NH=6, hd=32)
#define BATCH 32
#define HW 64
#define L 4096
#define CDIM 192
#define NHEADS 6
#define HD 32
#define NTOK 131072          // B * L
#define QKVC 576             // 3*C
#define CH 768               // 4*C

// window-order token row -> source row in [B, 64, 64] layout (shift -4,-4
// fused): row = win*64 + n.
__device__ __forceinline__ int srcrow_of(int row) {
  int win = row >> 6, n = row & 63;
  int bb = win >> 6, wid = win & 63;
  int i = ((wid >> 3) << 3) + (n >> 3);
  int j = ((wid & 7) << 3) + (n & 7);
  return bb * L + ((i + 4) & 63) * HW + ((j + 4) & 63);
}

// ---------------------------------------------------------------------------
// Fused LN1 + shift + window-partition + qkv GEMM:
//   Q[row, n] = sum_k LN(x[src(row)])[k] * qkv_w[n,k] + qkv_b[n]
// BM=128 BN=64 BK=32, 4 waves, XCD-swizzled grid (9 x 1024).
// Prologue computes per-row mean/rstd (2 threads/row); staging applies LN
// during the f32->bf16 convert. Each BK slab of a row = exactly one 128B
// line -> line-efficient despite the permuted row order.
// ---------------------------------------------------------------------------
__global__ __launch_bounds__(256) void gemm_ln_qkv(
    const float* __restrict__ X,      // x [NTOK,192] f32
    const float* __restrict__ g1,     // norm1 gamma [192]
    const float* __restrict__ bt1,    // norm1 beta [192]
    const float* __restrict__ W,      // qkv_w [576,192] f32
    const float* __restrict__ bias,   // qkv_b [576]
    bf16* __restrict__ Cout) {        // Q [NTOK,576] bf16
  __shared__ alignas(16) bf16 As[128 * 32];
  __shared__ alignas(16) bf16 Bs[64 * 32];
  __shared__ float MuS[128], RsS[128];
  const int gx = gridDim.x;                      // 9
  const int nb = gx * gridDim.y;                 // 9216
  const int id = blockIdx.y * gx + blockIdx.x;
  const int per = nb >> 3;
  const int jj = ((id & 7) * per) + (id >> 3);   // bijective, nb%8==0
  const int n0 = (jj % gx) * 64;
  const int m0 = (jj / gx) * 128;
  const int tid = threadIdx.x;
  const int lane = tid & 63;
  const int wave = tid >> 6;
  const int wm = (wave >> 1) * 64;
  const int wn = (wave & 1) * 32;
  const int lr = lane & 15;
  const int quad = lane >> 4;

  // prologue: LN stats, 2 threads per row
  {
    int row = tid >> 1, half = tid & 1;
    const float* xp = X + (size_t)srcrow_of(m0 + row) * CDIM + half * 96;
    float s1 = 0.f, s2 = 0.f;
#pragma unroll
    for (int i = 0; i < 24; i++) {
      float4 v = *(const float4*)(xp + i * 4);
      s1 += v.x + v.y + v.z + v.w;
      s2 = fmaf(v.x, v.x, fmaf(v.y, v.y, fmaf(v.z, v.z, fmaf(v.w, v.w, s2))));
    }
    s1 += __shfl_xor(s1, 1, 64);
    s2 += __shfl_xor(s2, 1, 64);
    if (!half) {
      float mean = s1 * (1.0f / 192.0f);
      float var = fmaxf(s2 * (1.0f / 192.0f) - mean * mean, 0.0f);
      MuS[row] = mean;
      RsS[row] = rsqrtf(var + 1e-5f);
    }
  }
  __syncthreads();

  f32x4 acc[4][2];
#pragma unroll
  for (int i = 0; i < 4; i++)
#pragma unroll
    for (int j = 0; j < 2; j++) acc[i][j] = (f32x4){0.f, 0.f, 0.f, 0.f};

  const int arow = tid >> 2;        // 0..63
  const int akq = (tid & 3) * 8;    // 0,8,16,24
  const size_t sa = (size_t)srcrow_of(m0 + arow) * CDIM;
  const size_t sb = (size_t)srcrow_of(m0 + arow + 64) * CDIM;

  for (int k0 = 0; k0 < CDIM; k0 += 32) {
    float4 ga = *(const float4*)(g1 + k0 + akq);
    float4 gb = *(const float4*)(g1 + k0 + akq + 4);
    float4 ba = *(const float4*)(bt1 + k0 + akq);
    float4 bb = *(const float4*)(bt1 + k0 + akq + 4);
    {
      float4 v0 = *(const float4*)(X + sa + k0 + akq);
      float4 v1 = *(const float4*)(X + sa + k0 + akq + 4);
      float mu = MuS[arow], rs = RsS[arow];
      bf16x8 p;
      p[0] = (bf16)((v0.x - mu) * rs * ga.x + ba.x);
      p[1] = (bf16)((v0.y - mu) * rs * ga.y + ba.y);
      p[2] = (bf16)((v0.z - mu) * rs * ga.z + ba.z);
      p[3] = (bf16)((v0.w - mu) * rs * ga.w + ba.w);
      p[4] = (bf16)((v1.x - mu) * rs * gb.x + bb.x);
      p[5] = (bf16)((v1.y - mu) * rs * gb.y + bb.y);
      p[6] = (bf16)((v1.z - mu) * rs * gb.z + bb.z);
      p[7] = (bf16)((v1.w - mu) * rs * gb.w + bb.w);
      *(bf16x8*)(&As[arow * 32 + akq]) = p;
    }
    {
      float4 v0 = *(const float4*)(X + sb + k0 + akq);
      float4 v1 = *(const float4*)(X + sb + k0 + akq + 4);
      float mu = MuS[arow + 64], rs = RsS[arow + 64];
      bf16x8 p;
      p[0] = (bf16)((v0.x - mu) * rs * ga.x + ba.x);
      p[1] = (bf16)((v0.y - mu) * rs * ga.y + ba.y);
      p[2] = (bf16)((v0.z - mu) * rs * ga.z + ba.z);
      p[3] = (bf16)((v0.w - mu) * rs * ga.w + ba.w);
      p[4] = (bf16)((v1.x - mu) * rs * gb.x + bb.x);
      p[5] = (bf16)((v1.y - mu) * rs * gb.y + bb.y);
      p[6] = (bf16)((v1.z - mu) * rs * gb.z + bb.z);
      p[7] = (bf16)((v1.w - mu) * rs * gb.w + bb.w);
      *(bf16x8*)(&As[(arow + 64) * 32 + akq]) = p;
    }
    {
      const float* Wp = W + (size_t)(n0 + arow) * CDIM + k0 + akq;
      float4 w0 = *(const float4*)Wp;
      float4 w1 = *(const float4*)(Wp + 4);
      bf16x8 bw;
      bw[0] = (bf16)w0.x; bw[1] = (bf16)w0.y; bw[2] = (bf16)w0.z; bw[3] = (bf16)w0.w;
      bw[4] = (bf16)w1.x; bw[5] = (bf16)w1.y; bw[6] = (bf16)w1.z; bw[7] = (bf16)w1.w;
      *(bf16x8*)(&Bs[arow * 32 + akq]) = bw;
    }
    __syncthreads();

    bf16x8 af[4], bfr[2];
#pragma unroll
    for (int mi = 0; mi < 4; mi++)
      af[mi] = *(const bf16x8*)(&As[(wm + mi * 16 + lr) * 32 + quad * 8]);
#pragma unroll
    for (int nj = 0; nj < 2; nj++)
      bfr[nj] = *(const bf16x8*)(&Bs[(wn + nj * 16 + lr) * 32 + quad * 8]);
#pragma unroll
    for (int mi = 0; mi < 4; mi++)
#pragma unroll
      for (int nj = 0; nj < 2; nj++)
        acc[mi][nj] = __builtin_amdgcn_mfma_f32_16x16x32_bf16(af[mi], bfr[nj],
                                                              acc[mi][nj], 0, 0, 0);
    __syncthreads();
  }

#pragma unroll
  for (int mi = 0; mi < 4; mi++) {
#pragma unroll
    for (int nj = 0; nj < 2; nj++) {
      int col = n0 + wn + nj * 16 + lr;
      float bv = bias[col];
#pragma unroll
      for (int r = 0; r < 4; r++) {
        int row = m0 + wm + mi * 16 + quad * 4 + r;
        Cout[(size_t)row * QKVC + col] = (bf16)(acc[mi][nj][r] + bv);
      }
    }
  }
}

// ---------------------------------------------------------------------------
// GEMM: C[M,N] = A[M,K] @ W[N,K]^T + bias (proj path). A bf16, W f32.
// BM=128 BN=64 BK=32, 4 waves, XCD-swizzled grid.
// EPI 3: +bias + window-reverse + roll(+4,+4) + residual res (f32).
// ---------------------------------------------------------------------------
template <int EPI, typename TR, typename TO>
__global__ __launch_bounds__(256) void gemm_bt(const bf16* __restrict__ A,
                                               const float* __restrict__ W,
                                               const float* __restrict__ bias,
                                               const TR* __restrict__ res,
                                               TO* __restrict__ Cout,
                                               int M, int N, int K, int ldw) {
  __shared__ alignas(16) bf16 As[128 * 32];
  __shared__ alignas(16) bf16 Bs[64 * 32];
  const int gx = gridDim.x;
  const int nb = gx * gridDim.y;
  const int id = blockIdx.y * gx + blockIdx.x;
  const int per = nb >> 3;
  const int jj = ((id & 7) * per) + (id >> 3);   // nb % 8 == 0 guaranteed
  const int n0 = (jj % gx) * 64;
  const int m0 = (jj / gx) * 128;
  const int tid = threadIdx.x;
  const int lane = tid & 63;
  const int wave = tid >> 6;
  const int wm = (wave >> 1) * 64;
  const int wn = (wave & 1) * 32;
  const int lr = lane & 15;
  const int quad = lane >> 4;

  f32x4 acc[4][2];
#pragma unroll
  for (int i = 0; i < 4; i++)
#pragma unroll
    for (int j = 0; j < 2; j++) acc[i][j] = (f32x4){0.f, 0.f, 0.f, 0.f};

  const int arow = tid >> 2;        // 0..63
  const int akq = (tid & 3) * 8;    // 0,8,16,24

  for (int k0 = 0; k0 < K; k0 += 32) {
    const bf16* Ap = A + (size_t)(m0 + arow) * K + k0 + akq;
    *(uint4*)(&As[arow * 32 + akq]) = *(const uint4*)Ap;
    *(uint4*)(&As[(arow + 64) * 32 + akq]) = *(const uint4*)(Ap + (size_t)64 * K);
    const float* Wp = W + (size_t)(n0 + arow) * ldw + k0 + akq;
    float4 w0 = *(const float4*)Wp;
    float4 w1 = *(const float4*)(Wp + 4);
    bf16x8 bw;
    bw[0] = (bf16)w0.x; bw[1] = (bf16)w0.y; bw[2] = (bf16)w0.z; bw[3] = (bf16)w0.w;
    bw[4] = (bf16)w1.x; bw[5] = (bf16)w1.y; bw[6] = (bf16)w1.z; bw[7] = (bf16)w1.w;
    *(bf16x8*)(&Bs[arow * 32 + akq]) = bw;
    __syncthreads();

    bf16x8 af[4], bfr[2];
#pragma unroll
    for (int mi = 0; mi < 4; mi++)
      af[mi] = *(const bf16x8*)(&As[(wm + mi * 16 + lr) * 32 + quad * 8]);
#pragma unroll
    for (int nj = 0; nj < 2; nj++)
      bfr[nj] = *(const bf16x8*)(&Bs[(wn + nj * 16 + lr) * 32 + quad * 8]);
#pragma unroll
    for (int mi = 0; mi < 4; mi++)
#pragma unroll
      for (int nj = 0; nj < 2; nj++)
        acc[mi][nj] = __builtin_amdgcn_mfma_f32_16x16x32_bf16(af[mi], bfr[nj],
                                                              acc[mi][nj], 0, 0, 0);
    __syncthreads();
  }

#pragma unroll
  for (int mi = 0; mi < 4; mi++) {
#pragma unroll
    for (int nj = 0; nj < 2; nj++) {
      int col = n0 + wn + nj * 16 + lr;
      float bv = bias[col];
#pragma unroll
      for (int r = 0; r < 4; r++) {
        int row = m0 + wm + mi * 16 + quad * 4 + r;
        float v = acc[mi][nj][r] + bv;
        size_t didx;
        if (EPI == 3) {
          didx = ((size_t)srcrow_of(row)) * (size_t)N + col;
          v += (float)res[didx];
        } else {
          didx = (size_t)row * N + col;
        }
        Cout[didx] = (TO)v;
      }
    }
  }
}

// ---------------------------------------------------------------------------
// Attention: one wave per (window, head). grid = (2048, 6), block = 64.
// LDS overlay: Ps reuses Qs+Ks (single wave -> DS ops program-ordered).
// ---------------------------------------------------------------------------
__device__ __forceinline__ int region64(int h) {
  return (h < 56) ? 0 : ((h < 60) ? 1 : 2);
}

__global__ __launch_bounds__(64) void attn_kernel(const bf16* __restrict__ qkv,
                                                  const float* __restrict__ rpb,
                                                  bf16* __restrict__ out) {
  __shared__ alignas(16) bf16 QKP[64 * 64];   // Qs | Ks, later reused as Ps
  __shared__ alignas(16) bf16 Vt[32 * 64];
  bf16* Qs = QKP;
  bf16* Ks = QKP + 64 * 32;
  bf16* Ps = QKP;
  const int win = blockIdx.x;
  const int head = blockIdx.y;
  const int lane = threadIdx.x;
  const int lr = lane & 15;
  const int quad = lane >> 4;
  const int wid = win & 63;
  const int wi = wid >> 3, wj = wid & 7;

  const bf16* base = qkv + (size_t)win * 64 * QKVC + head * HD;
#pragma unroll
  for (int rep = 0; rep < 4; rep++) {
    int r = (lane >> 2) + rep * 16;
    int c = (lane & 3) * 8;
    *(uint4*)(&Qs[r * 32 + c]) = *(const uint4*)(base + (size_t)r * QKVC + c);
    *(uint4*)(&Ks[r * 32 + c]) = *(const uint4*)(base + CDIM + (size_t)r * QKVC + c);
    uint4 vv = *(const uint4*)(base + 2 * CDIM + (size_t)r * QKVC + c);
    bf16x8 v8 = __builtin_bit_cast(bf16x8, vv);
#pragma unroll
    for (int j = 0; j < 8; j++) Vt[(c + j) * 64 + r] = v8[j];
  }
  __syncthreads();

  f32x4 s[4][4];
  {
    bf16x8 qf[4], kf[4];
#pragma unroll
    for (int mi = 0; mi < 4; mi++)
      qf[mi] = *(const bf16x8*)(&Qs[(mi * 16 + lr) * 32 + quad * 8]);
#pragma unroll
    for (int nj = 0; nj < 4; nj++)
      kf[nj] = *(const bf16x8*)(&Ks[(nj * 16 + lr) * 32 + quad * 8]);
#pragma unroll
    for (int mi = 0; mi < 4; mi++)
#pragma unroll
      for (int nj = 0; nj < 4; nj++)
        s[mi][nj] = __builtin_amdgcn_mfma_f32_16x16x32_bf16(
            qf[mi], kf[nj], (f32x4){0.f, 0.f, 0.f, 0.f}, 0, 0, 0);
  }

  const float scale = 0.17677669529663687f;
#pragma unroll
  for (int mi = 0; mi < 4; mi++) {
#pragma unroll
    for (int nj = 0; nj < 4; nj++) {
#pragma unroll
      for (int r = 0; r < 4; r++) {
        int rr = mi * 16 + quad * 4 + r;
        int cc = nj * 16 + lr;
        int qi = rr >> 3, qj = rr & 7, ki = cc >> 3, kj = cc & 7;
        int idx = (qi - ki + 7) * 15 + (qj - kj + 7);
        float bv = rpb[idx * NHEADS + head];
        int regr = 3 * region64(wi * 8 + qi) + region64(wj * 8 + qj);
        int regc = 3 * region64(wi * 8 + ki) + region64(wj * 8 + kj);
        float mv = (regr != regc) ? -100.0f : 0.0f;
        s[mi][nj][r] = s[mi][nj][r] * scale + bv + mv;
      }
    }
  }

#pragma unroll
  for (int mi = 0; mi < 4; mi++) {
#pragma unroll
    for (int r = 0; r < 4; r++) {
      float mx = s[mi][0][r];
#pragma unroll
      for (int nj = 1; nj < 4; nj++) mx = fmaxf(mx, s[mi][nj][r]);
#pragma unroll
      for (int off = 1; off < 16; off <<= 1) mx = fmaxf(mx, __shfl_xor(mx, off, 64));
      float sum = 0.f;
#pragma unroll
      for (int nj = 0; nj < 4; nj++) {
        float p = __expf(s[mi][nj][r] - mx);
        s[mi][nj][r] = p;
        sum += p;
      }
#pragma unroll
      for (int off = 1; off < 16; off <<= 1) sum += __shfl_xor(sum, off, 64);
      float inv = 1.0f / sum;
#pragma unroll
      for (int nj = 0; nj < 4; nj++) s[mi][nj][r] *= inv;
    }
  }

#pragma unroll
  for (int mi = 0; mi < 4; mi++)
#pragma unroll
    for (int nj = 0; nj < 4; nj++)
#pragma unroll
      for (int r = 0; r < 4; r++)
        Ps[(mi * 16 + quad * 4 + r) * 64 + nj * 16 + lr] = (bf16)s[mi][nj][r];
  __syncthreads();

  f32x4 o[4][2];
#pragma unroll
  for (int mi = 0; mi < 4; mi++)
#pragma unroll
    for (int nj = 0; nj < 2; nj++) o[mi][nj] = (f32x4){0.f, 0.f, 0.f, 0.f};
#pragma unroll
  for (int ks = 0; ks < 2; ks++) {
    bf16x8 pf[4], vf[2];
#pragma unroll
    for (int mi = 0; mi < 4; mi++)
      pf[mi] = *(const bf16x8*)(&Ps[(mi * 16 + lr) * 64 + ks * 32 + quad * 8]);
#pragma unroll
    for (int nj = 0; nj < 2; nj++)
      vf[nj] = *(const bf16x8*)(&Vt[(nj * 16 + lr) * 64 + ks * 32 + quad * 8]);
#pragma unroll
    for (int mi = 0; mi < 4; mi++)
#pragma unroll
      for (int nj = 0; nj < 2; nj++)
        o[mi][nj] = __builtin_amdgcn_mfma_f32_16x16x32_bf16(pf[mi], vf[nj],
                                                            o[mi][nj], 0, 0, 0);
  }

#pragma unroll
  for (int mi = 0; mi < 4; mi++)
#pragma unroll
    for (int nj = 0; nj < 2; nj++)
#pragma unroll
      for (int r = 0; r < 4; r++) {
        size_t row = (size_t)win * 64 + mi * 16 + quad * 4 + r;
        int col = head * HD + nj * 16 + lr;
        out[row * CDIM + col] = (bf16)o[mi][nj][r];
      }
}

// ---------------------------------------------------------------------------
// Weight pre-conversion, PRE-SWIZZLED for linear global_load_lds staging.
//   W1b[h*192 + gs*8 + e]          = fc1_w[h*192 + g*8 + e],
//       g = (gs & ~7) | ((gs & 7) ^ (h & 7))
//   W2b[c*12288 + n*64 + gs*8 + e] = fc2_w[n*768 + c*64 + g*8 + e],
//       g = gs ^ (n & 7)
// ---------------------------------------------------------------------------
__global__ __launch_bounds__(256) void wconv_kernel(const float* __restrict__ fc1w,
                                                    const float* __restrict__ fc2w,
                                                    bf16* __restrict__ W1b,
                                                    bf16* __restrict__ W2b) {
  int i = blockIdx.x * 256 + threadIdx.x;   // 0..147455
  {
    int h = i / 192;
    int cc = i - h * 192;
    int gs = cc >> 3, e = cc & 7;
    int g = (gs & ~7) | ((gs & 7) ^ (h & 7));
    W1b[i] = (bf16)fc1w[h * 192 + g * 8 + e];
  }
  {
    int c = i / 12288;
    int rem = i - c * 12288;
    int n = rem >> 6;
    int cc = rem & 63;
    int gs = cc >> 3, e = cc & 7;
    int g = gs ^ (n & 7);
    W2b[i] = (bf16)fc2w[n * 768 + c * 64 + g * 8 + e];
  }
}

// ---------------------------------------------------------------------------
// Fused LN2 + MLP v4: out = x1 + fc2_b + gelu(LN(x1)@fc1^T + b1)@fc2^T.
// Wave-owned-rows (128 tokens / 8 waves / block, 16 rows/wave).
// fc1 computed with SWAPPED operands -> mfma(W1frag, Afrag) yields H^T in
// C-layout: lane (quad,lr) holds h = hj*16+quad*4+{0..3} of token lr -> 4
// CONSECUTIVE hidden elems. Hs is [16 tok][64 h] written with 4 packed
// bf16x4 (8B) stores per chunk instead of 16 scalar b16 column writes.
// XOR key (lr&7)<<1 keeps granule bit0 -> 16B-aligned fc2 reads.
// ---------------------------------------------------------------------------
__global__ __launch_bounds__(512, 4) void mlp_fused(
    const bf16* __restrict__ X1,    // [NTOK,192] bf16 (attn residual sum)
    const float* __restrict__ g2,   // norm2 gamma [192]
    const float* __restrict__ bt2,  // norm2 beta  [192]
    const bf16* __restrict__ W1b,   // [768,192] pre-swizzled
    const bf16* __restrict__ W2b,   // [12][192][64] pre-swizzled
    const float* __restrict__ b1,   // [768]
    const float* __restrict__ b2,   // [192]
    float* __restrict__ out) {      // [NTOK,192] f32
  __shared__ alignas(16) bf16 W1s[64 * 192];     // 24 KiB
  __shared__ alignas(16) bf16 W2s[192 * 64];     // 24 KiB
  __shared__ alignas(16) bf16 Hs[8][16 * 64];    // 16 KiB, wave-private slices
  __shared__ float Gs[192], Bn[192];             // 1.5 KiB LN params

  const int tid = threadIdx.x;
  const int lane = tid & 63;
  const int wave = tid >> 6;
  const int lr = lane & 15;
  const int quad = lane >> 4;
  const int m0 = blockIdx.x * 128;
  const int arow = m0 + wave * 16 + lr;          // this lane's A row

  if (tid < 192) { Gs[tid] = g2[tid]; Bn[tid] = bt2[tid]; }
  __syncthreads();

  // Load X1 rows + fused LN2 -> A fragments (bf16) in registers.
  bf16x8 xr[6];
  {
    const bf16* xp = X1 + (size_t)arow * CDIM + quad * 8;
#pragma unroll
    for (int ks = 0; ks < 6; ks++) xr[ks] = *(const bf16x8*)(xp + ks * 32);
  }
  float s1 = 0.f, s2 = 0.f;
#pragma unroll
  for (int ks = 0; ks < 6; ks++)
#pragma unroll
    for (int j = 0; j < 8; j++) {
      float v = (float)xr[ks][j];
      s1 += v;
      s2 = fmaf(v, v, s2);
    }
  s1 += __shfl_xor(s1, 16, 64); s1 += __shfl_xor(s1, 32, 64);
  s2 += __shfl_xor(s2, 16, 64); s2 += __shfl_xor(s2, 32, 64);
  float mean = s1 * (1.0f / 192.0f);
  float var = fmaxf(s2 * (1.0f / 192.0f) - mean * mean, 0.0f);
  float rstd = rsqrtf(var + 1e-5f);
  bf16x8 aF[6];
#pragma unroll
  for (int ks = 0; ks < 6; ks++) {
    int cb = ks * 32 + quad * 8;
    bf16x8 a;
#pragma unroll
    for (int j = 0; j < 8; j++)
      a[j] = (bf16)(((float)xr[ks][j] - mean) * rstd * Gs[cb + j] + Bn[cb + j]);
    aF[ks] = a;
  }

  f32x4 oacc[12];
#pragma unroll
  for (int nt = 0; nt < 12; nt++) oacc[nt] = (f32x4){0.f, 0.f, 0.f, 0.f};

  for (int c = 0; c < 12; c++) {
    const int h0 = c * 64;
    // stage W1 + W2 chunks via global_load_lds: 3+3 issues of 16B/lane.
    {
      const size_t cb = (size_t)c * 24576;       // chunk stride in bytes
      const int off = wave * 1024 + lane * 16;
      const char* gp1 = (const char*)W1b + cb + off;
      const char* gp2 = (const char*)W2b + cb + off;
      char* l1 = (char*)W1s + wave * 1024;
      char* l2 = (char*)W2s + wave * 1024;
#pragma unroll
      for (int i = 0; i < 3; i++) {
        __builtin_amdgcn_global_load_lds((gchar*)(gp1 + i * 8192),
                                         (lchar*)(l1 + i * 8192), 16, 0, 0);
        __builtin_amdgcn_global_load_lds((gchar*)(gp2 + i * 8192),
                                         (lchar*)(l2 + i * 8192), 16, 0, 0);
      }
    }
    __syncthreads();   // W1s/W2s ready

    // fc1 (swapped): hacc[hj][r] = H^T[h = hj*16+quad*4+r][t = lr]
    f32x4 hacc[4];
#pragma unroll
    for (int hj = 0; hj < 4; hj++) hacc[hj] = (f32x4){0.f, 0.f, 0.f, 0.f};
#pragma unroll
    for (int ks = 0; ks < 6; ks++) {
      int c8 = ks * 4 + quad;
      int base = (c8 & ~7) | ((c8 & 7) ^ (lr & 7));
#pragma unroll
      for (int hj = 0; hj < 4; hj++) {
        bf16x8 wf = *(const bf16x8*)(&W1s[(hj * 16 + lr) * 192 + base * 8]);
        hacc[hj] = __builtin_amdgcn_mfma_f32_16x16x32_bf16(wf, aF[ks], hacc[hj], 0, 0, 0);
      }
    }

    // bias + gelu (A&S 7.1.26 erf) -> packed transposed write: Hs[t][h],
    // 4 consecutive h per (hj) -> one bf16x4 (8B) store.
#pragma unroll
    for (int hj = 0; hj < 4; hj++) {
      float4 bh4 = *(const float4*)(&b1[h0 + hj * 16 + quad * 4]);
      float bhv[4] = {bh4.x, bh4.y, bh4.z, bh4.w};
      bf16x4 pk;
#pragma unroll
      for (int r = 0; r < 4; r++) {
        float h = hacc[hj][r] + bhv[r];
        float x = fabsf(h) * 0.70710678118654752f;
        float t = __fdividef(1.0f, fmaf(0.3275911f, x, 1.0f));
        float p = t * (0.254829592f +
                  t * (-0.284496736f +
                  t * (1.421413741f +
                  t * (-1.453152027f + t * 1.061405429f))));
        float er = fmaf(-p, __expf(-x * x), 1.0f);   // erf(|h|/sqrt2)
        er = copysignf(er, h);
        pk[r] = (bf16)(0.5f * h * (1.0f + er));
      }
      int gw = (hj * 4 + quad) ^ ((lr & 7) << 1);
      *(bf16x4*)(&Hs[wave][lr * 64 + gw * 4]) = pk;
    }
    // no __syncthreads: Hs[wave] is wave-private (lgkmcnt orders the hazard).

    // fc2: oacc[16x192] += H[16x64] @ W2chunk[192x64]^T
#pragma unroll
    for (int ks = 0; ks < 2; ks++) {
      int gr = (ks * 8 + quad * 2) ^ ((lr & 7) << 1);
      bf16x8 hF = *(const bf16x8*)(&Hs[wave][lr * 64 + gr * 4]);
      int c8 = ks * 4 + quad;
      int c8s = c8 ^ (lr & 7);
#pragma unroll
      for (int nt = 0; nt < 12; nt++) {
        bf16x8 wF = *(const bf16x8*)(&W2s[(nt * 16 + lr) * 64 + c8s * 8]);
        oacc[nt] = __builtin_amdgcn_mfma_f32_16x16x32_bf16(hF, wF, oacc[nt], 0, 0, 0);
      }
    }
    __syncthreads();   // W1s/W2s consumed; safe to restage next chunk
  }

  // epilogue: + fc2_b + residual x1, store f32.
#pragma unroll
  for (int nt = 0; nt < 12; nt++) {
    float fb = b2[nt * 16 + lr];
#pragma unroll
    for (int r = 0; r < 4; r++) {
      size_t row = (size_t)(m0 + wave * 16 + quad * 4 + r);
      size_t idx = row * CDIM + nt * 16 + lr;
      out[idx] = oacc[nt][r] + fb + (float)X1[idx];
    }
  }
}

// ---------------------------------------------------------------------------
// Workspace (peak ~192 MiB):
//   phase 1: Q [0, 150,994,944)  qkv ; T [150,994,944, 201,326,592) attn out
//   phase 2: X1 [0, 50,331,648) ; W1b/W2b at [52,428,800, +589,824)
// ---------------------------------------------------------------------------
extern "C" void kernel_launch(void* const* d_in, const int* in_sizes, int n_in,
                              void* d_out, int out_size, void* d_ws, size_t ws_size,
                              hipStream_t stream) {
  const float* x      = (const float*)d_in[0];
  const float* n1g    = (const float*)d_in[3];
  const float* n1b    = (const float*)d_in[4];
  const float* qkv_w  = (const float*)d_in[5];
  const float* qkv_b  = (const float*)d_in[6];
  const float* rpb    = (const float*)d_in[7];
  const float* proj_w = (const float*)d_in[8];
  const float* proj_b = (const float*)d_in[9];
  const float* n2g    = (const float*)d_in[10];
  const float* n2b    = (const float*)d_in[11];
  const float* fc1_w  = (const float*)d_in[12];
  const float* fc1_b  = (const float*)d_in[13];
  const float* fc2_w  = (const float*)d_in[14];
  const float* fc2_b  = (const float*)d_in[15];
  float* out = (float*)d_out;

  char* wsb = (char*)d_ws;
  bf16* Q   = (bf16*)wsb;                        // phase 1: qkv 151 MB
  bf16* X1  = (bf16*)wsb;                        // phase 2: x1 50 MB
  bf16* W1b = (bf16*)(wsb + 52428800ull);        // 294,912 B
  bf16* W2b = (bf16*)(wsb + 52428800ull + 294912ull);
  bf16* T   = (bf16*)(wsb + 150994944ull);       // attn out

  // 1. fused LN1 + shift + window partition + qkv GEMM: x -> Q
  gemm_ln_qkv<<<dim3(9, 1024), 256, 0, stream>>>(x, n1g, n1b, qkv_w, qkv_b, Q);
  // 2. windowed attention: Q -> T
  attn_kernel<<<dim3(2048, 6), 64, 0, stream>>>(Q, rpb, T);
  // 3. proj + window reverse + roll + residual(x): T -> X1 (Q dead)
  gemm_bt<3, float, bf16><<<dim3(3, 1024), 256, 0, stream>>>(
      T, proj_w, proj_b, x, X1, NTOK, CDIM, CDIM, CDIM);
  // 3b. weight conversion (region freed by Q)
  wconv_kernel<<<576, 256, 0, stream>>>(fc1_w, fc2_w, W1b, W2b);
  // 4. fused LN2 + MLP + residual -> out (128 tokens/block, 8 waves)
  mlp_fused<<<1024, 512, 0, stream>>>(X1, n2g, n2b, W1b, W2b, fc1_b, fc2_b, out);
}

// Round 7
// 541.809 us; speedup vs baseline: 1.2048x; 1.2048x over previous
//
#include <hip/hip_runtime.h>
#include <hip/hip_bf16.h>
#include <math.h>

typedef __bf16 bf16;
typedef __bf16 bf16x4 __attribute__((ext_vector_type(4)));
typedef __bf16 bf16x8 __attribute__((ext_vector_type(8)));
typedef float f32x4 __attribute__((ext_vector_type(4)));

typedef const __attribute__((address_space(1))) char gchar;
typedef __attribute__((address_space(3))) char lchar;

// Problem constants (B=32, H=W=64, C=192, WS=8, SHIFT=4, NH=6, hd=32)
#define BATCH 32
#define HW 64
#define L 4096
#define CDIM 192
#define NHEADS 6
#define HD 32
#define NTOK 131072          // B * L
#define QKVC 576             // 3*C
#define CH 768               // 4*C

// window-order token row -> source row in [B, 64, 64] layout (shift -4,-4
// fused): row = win*64 + n.
__device__ __forceinline__ int srcrow_of(int row) {
  int win = row >> 6, n = row & 63;
  int bb = win >> 6, wid = win & 63;
  int i = ((wid >> 3) << 3) + (n >> 3);
  int j = ((wid & 7) << 3) + (n & 7);
  return bb * L + ((i + 4) & 63) * HW + ((j + 4) & 63);
}

// ---------------------------------------------------------------------------
// LayerNorm pass (LN1). PERM=true fuses cyclic shift (-4,-4) + window
// partition into the store order. One wave per token.
// NOTE (round-6 lesson): keep LN1 as its own streaming pass. Fusing it into
// the qkv GEMM's A-staging duplicates the LN work x9 (one per n-tile block)
// and doubles staged bytes (f32 vs bf16) -> measured 228 us vs ~140 split.
// ---------------------------------------------------------------------------
template <bool PERM, typename TIN>
__global__ __launch_bounds__(256) void ln_kernel(const TIN* __restrict__ xin,
                                                 const float* __restrict__ g,
                                                 const float* __restrict__ bta,
                                                 bf16* __restrict__ yout) {
  int wave = threadIdx.x >> 6;
  int lane = threadIdx.x & 63;
  int tok = blockIdx.x * 4 + wave;
  int src = PERM ? srcrow_of(tok) : tok;
  const TIN* sp = xin + (size_t)src * CDIM;
  float v0 = (float)sp[lane];
  float v1 = (float)sp[lane + 64];
  float v2 = (float)sp[lane + 128];
  float s = v0 + v1 + v2;
#pragma unroll
  for (int off = 32; off; off >>= 1) s += __shfl_xor(s, off, 64);
  float mean = s * (1.0f / 192.0f);
  float d0 = v0 - mean, d1 = v1 - mean, d2 = v2 - mean;
  float q = d0 * d0 + d1 * d1 + d2 * d2;
#pragma unroll
  for (int off = 32; off; off >>= 1) q += __shfl_xor(q, off, 64);
  float rstd = rsqrtf(q * (1.0f / 192.0f) + 1e-5f);
  bf16* dp = yout + (size_t)tok * CDIM;
  dp[lane]       = (bf16)(d0 * rstd * g[lane]       + bta[lane]);
  dp[lane + 64]  = (bf16)(d1 * rstd * g[lane + 64]  + bta[lane + 64]);
  dp[lane + 128] = (bf16)(d2 * rstd * g[lane + 128] + bta[lane + 128]);
}

// ---------------------------------------------------------------------------
// GEMM: C[M,N] = A[M,K] @ W[N,K]^T + bias. A bf16, W f32 (converted while
// staging). BM=128 BN=64 BK=32, 4 waves, XCD-swizzled grid (T1, bijective
// since nb%8==0).
// EPI 0: +bias. 3: +bias + window-reverse + roll(+4,+4) + residual res (f32)
// written at permuted location.
// ---------------------------------------------------------------------------
template <int EPI, typename TR, typename TO>
__global__ __launch_bounds__(256) void gemm_bt(const bf16* __restrict__ A,
                                               const float* __restrict__ W,
                                               const float* __restrict__ bias,
                                               const TR* __restrict__ res,
                                               TO* __restrict__ Cout,
                                               int M, int N, int K, int ldw) {
  __shared__ alignas(16) bf16 As[128 * 32];
  __shared__ alignas(16) bf16 Bs[64 * 32];
  const int gx = gridDim.x;
  const int nb = gx * gridDim.y;
  const int id = blockIdx.y * gx + blockIdx.x;
  const int per = nb >> 3;
  const int jj = ((id & 7) * per) + (id >> 3);   // nb % 8 == 0 guaranteed
  const int n0 = (jj % gx) * 64;
  const int m0 = (jj / gx) * 128;
  const int tid = threadIdx.x;
  const int lane = tid & 63;
  const int wave = tid >> 6;
  const int wm = (wave >> 1) * 64;
  const int wn = (wave & 1) * 32;
  const int lr = lane & 15;
  const int quad = lane >> 4;

  f32x4 acc[4][2];
#pragma unroll
  for (int i = 0; i < 4; i++)
#pragma unroll
    for (int j = 0; j < 2; j++) acc[i][j] = (f32x4){0.f, 0.f, 0.f, 0.f};

  const int arow = tid >> 2;        // 0..63
  const int akq = (tid & 3) * 8;    // 0,8,16,24

  for (int k0 = 0; k0 < K; k0 += 32) {
    const bf16* Ap = A + (size_t)(m0 + arow) * K + k0 + akq;
    *(uint4*)(&As[arow * 32 + akq]) = *(const uint4*)Ap;
    *(uint4*)(&As[(arow + 64) * 32 + akq]) = *(const uint4*)(Ap + (size_t)64 * K);
    const float* Wp = W + (size_t)(n0 + arow) * ldw + k0 + akq;
    float4 w0 = *(const float4*)Wp;
    float4 w1 = *(const float4*)(Wp + 4);
    bf16x8 bw;
    bw[0] = (bf16)w0.x; bw[1] = (bf16)w0.y; bw[2] = (bf16)w0.z; bw[3] = (bf16)w0.w;
    bw[4] = (bf16)w1.x; bw[5] = (bf16)w1.y; bw[6] = (bf16)w1.z; bw[7] = (bf16)w1.w;
    *(bf16x8*)(&Bs[arow * 32 + akq]) = bw;
    __syncthreads();

    bf16x8 af[4], bfr[2];
#pragma unroll
    for (int mi = 0; mi < 4; mi++)
      af[mi] = *(const bf16x8*)(&As[(wm + mi * 16 + lr) * 32 + quad * 8]);
#pragma unroll
    for (int nj = 0; nj < 2; nj++)
      bfr[nj] = *(const bf16x8*)(&Bs[(wn + nj * 16 + lr) * 32 + quad * 8]);
#pragma unroll
    for (int mi = 0; mi < 4; mi++)
#pragma unroll
      for (int nj = 0; nj < 2; nj++)
        acc[mi][nj] = __builtin_amdgcn_mfma_f32_16x16x32_bf16(af[mi], bfr[nj],
                                                              acc[mi][nj], 0, 0, 0);
    __syncthreads();
  }

#pragma unroll
  for (int mi = 0; mi < 4; mi++) {
#pragma unroll
    for (int nj = 0; nj < 2; nj++) {
      int col = n0 + wn + nj * 16 + lr;
      float bv = bias[col];
#pragma unroll
      for (int r = 0; r < 4; r++) {
        int row = m0 + wm + mi * 16 + quad * 4 + r;
        float v = acc[mi][nj][r] + bv;
        size_t didx;
        if (EPI == 3) {
          didx = ((size_t)srcrow_of(row)) * (size_t)N + col;
          v += (float)res[didx];
        } else {
          didx = (size_t)row * N + col;
        }
        Cout[didx] = (TO)v;
      }
    }
  }
}

// ---------------------------------------------------------------------------
// Attention: one wave per (window, head). grid = (2048, 6), block = 64.
// LDS overlay: Ps reuses Qs+Ks (single wave -> DS ops program-ordered).
// 12.3KB/block -> 13 blocks/CU.
// ---------------------------------------------------------------------------
__device__ __forceinline__ int region64(int h) {
  return (h < 56) ? 0 : ((h < 60) ? 1 : 2);
}

__global__ __launch_bounds__(64) void attn_kernel(const bf16* __restrict__ qkv,
                                                  const float* __restrict__ rpb,
                                                  bf16* __restrict__ out) {
  __shared__ alignas(16) bf16 QKP[64 * 64];   // Qs | Ks, later reused as Ps
  __shared__ alignas(16) bf16 Vt[32 * 64];
  bf16* Qs = QKP;
  bf16* Ks = QKP + 64 * 32;
  bf16* Ps = QKP;
  const int win = blockIdx.x;
  const int head = blockIdx.y;
  const int lane = threadIdx.x;
  const int lr = lane & 15;
  const int quad = lane >> 4;
  const int wid = win & 63;
  const int wi = wid >> 3, wj = wid & 7;

  const bf16* base = qkv + (size_t)win * 64 * QKVC + head * HD;
#pragma unroll
  for (int rep = 0; rep < 4; rep++) {
    int r = (lane >> 2) + rep * 16;
    int c = (lane & 3) * 8;
    *(uint4*)(&Qs[r * 32 + c]) = *(const uint4*)(base + (size_t)r * QKVC + c);
    *(uint4*)(&Ks[r * 32 + c]) = *(const uint4*)(base + CDIM + (size_t)r * QKVC + c);
    uint4 vv = *(const uint4*)(base + 2 * CDIM + (size_t)r * QKVC + c);
    bf16x8 v8 = __builtin_bit_cast(bf16x8, vv);
#pragma unroll
    for (int j = 0; j < 8; j++) Vt[(c + j) * 64 + r] = v8[j];
  }
  __syncthreads();

  f32x4 s[4][4];
  {
    bf16x8 qf[4], kf[4];
#pragma unroll
    for (int mi = 0; mi < 4; mi++)
      qf[mi] = *(const bf16x8*)(&Qs[(mi * 16 + lr) * 32 + quad * 8]);
#pragma unroll
    for (int nj = 0; nj < 4; nj++)
      kf[nj] = *(const bf16x8*)(&Ks[(nj * 16 + lr) * 32 + quad * 8]);
#pragma unroll
    for (int mi = 0; mi < 4; mi++)
#pragma unroll
      for (int nj = 0; nj < 4; nj++)
        s[mi][nj] = __builtin_amdgcn_mfma_f32_16x16x32_bf16(
            qf[mi], kf[nj], (f32x4){0.f, 0.f, 0.f, 0.f}, 0, 0, 0);
  }

  const float scale = 0.17677669529663687f;
#pragma unroll
  for (int mi = 0; mi < 4; mi++) {
#pragma unroll
    for (int nj = 0; nj < 4; nj++) {
#pragma unroll
      for (int r = 0; r < 4; r++) {
        int rr = mi * 16 + quad * 4 + r;
        int cc = nj * 16 + lr;
        int qi = rr >> 3, qj = rr & 7, ki = cc >> 3, kj = cc & 7;
        int idx = (qi - ki + 7) * 15 + (qj - kj + 7);
        float bv = rpb[idx * NHEADS + head];
        int regr = 3 * region64(wi * 8 + qi) + region64(wj * 8 + qj);
        int regc = 3 * region64(wi * 8 + ki) + region64(wj * 8 + kj);
        float mv = (regr != regc) ? -100.0f : 0.0f;
        s[mi][nj][r] = s[mi][nj][r] * scale + bv + mv;
      }
    }
  }

#pragma unroll
  for (int mi = 0; mi < 4; mi++) {
#pragma unroll
    for (int r = 0; r < 4; r++) {
      float mx = s[mi][0][r];
#pragma unroll
      for (int nj = 1; nj < 4; nj++) mx = fmaxf(mx, s[mi][nj][r]);
#pragma unroll
      for (int off = 1; off < 16; off <<= 1) mx = fmaxf(mx, __shfl_xor(mx, off, 64));
      float sum = 0.f;
#pragma unroll
      for (int nj = 0; nj < 4; nj++) {
        float p = __expf(s[mi][nj][r] - mx);
        s[mi][nj][r] = p;
        sum += p;
      }
#pragma unroll
      for (int off = 1; off < 16; off <<= 1) sum += __shfl_xor(sum, off, 64);
      float inv = 1.0f / sum;
#pragma unroll
      for (int nj = 0; nj < 4; nj++) s[mi][nj][r] *= inv;
    }
  }

#pragma unroll
  for (int mi = 0; mi < 4; mi++)
#pragma unroll
    for (int nj = 0; nj < 4; nj++)
#pragma unroll
      for (int r = 0; r < 4; r++)
        Ps[(mi * 16 + quad * 4 + r) * 64 + nj * 16 + lr] = (bf16)s[mi][nj][r];
  __syncthreads();

  f32x4 o[4][2];
#pragma unroll
  for (int mi = 0; mi < 4; mi++)
#pragma unroll
    for (int nj = 0; nj < 2; nj++) o[mi][nj] = (f32x4){0.f, 0.f, 0.f, 0.f};
#pragma unroll
  for (int ks = 0; ks < 2; ks++) {
    bf16x8 pf[4], vf[2];
#pragma unroll
    for (int mi = 0; mi < 4; mi++)
      pf[mi] = *(const bf16x8*)(&Ps[(mi * 16 + lr) * 64 + ks * 32 + quad * 8]);
#pragma unroll
    for (int nj = 0; nj < 2; nj++)
      vf[nj] = *(const bf16x8*)(&Vt[(nj * 16 + lr) * 64 + ks * 32 + quad * 8]);
#pragma unroll
    for (int mi = 0; mi < 4; mi++)
#pragma unroll
      for (int nj = 0; nj < 2; nj++)
        o[mi][nj] = __builtin_amdgcn_mfma_f32_16x16x32_bf16(pf[mi], vf[nj],
                                                            o[mi][nj], 0, 0, 0);
  }

#pragma unroll
  for (int mi = 0; mi < 4; mi++)
#pragma unroll
    for (int nj = 0; nj < 2; nj++)
#pragma unroll
      for (int r = 0; r < 4; r++) {
        size_t row = (size_t)win * 64 + mi * 16 + quad * 4 + r;
        int col = head * HD + nj * 16 + lr;
        out[row * CDIM + col] = (bf16)o[mi][nj][r];
      }
}

// ---------------------------------------------------------------------------
// Weight pre-conversion, PRE-SWIZZLED for linear global_load_lds staging.
//   W1b[h*192 + gs*8 + e]          = fc1_w[h*192 + g*8 + e],
//       g = (gs & ~7) | ((gs & 7) ^ (h & 7))
//   W2b[c*12288 + n*64 + gs*8 + e] = fc2_w[n*768 + c*64 + g*8 + e],
//       g = gs ^ (n & 7)
// ---------------------------------------------------------------------------
__global__ __launch_bounds__(256) void wconv_kernel(const float* __restrict__ fc1w,
                                                    const float* __restrict__ fc2w,
                                                    bf16* __restrict__ W1b,
                                                    bf16* __restrict__ W2b) {
  int i = blockIdx.x * 256 + threadIdx.x;   // 0..147455
  {
    int h = i / 192;
    int cc = i - h * 192;
    int gs = cc >> 3, e = cc & 7;
    int g = (gs & ~7) | ((gs & 7) ^ (h & 7));
    W1b[i] = (bf16)fc1w[h * 192 + g * 8 + e];
  }
  {
    int c = i / 12288;
    int rem = i - c * 12288;
    int n = rem >> 6;
    int cc = rem & 63;
    int gs = cc >> 3, e = cc & 7;
    int g = gs ^ (n & 7);
    W2b[i] = (bf16)fc2w[n * 768 + c * 64 + g * 8 + e];
  }
}

// ---------------------------------------------------------------------------
// Fused LN2 + MLP v4: out = x1 + fc2_b + gelu(LN(x1)@fc1^T + b1)@fc2^T.
// Wave-owned-rows (128 tokens / 8 waves / block, 16 rows/wave).
// fc1 computed with SWAPPED operands -> mfma(W1frag, Afrag) yields H^T in
// C-layout: lane (quad,lr) holds h = hj*16+quad*4+{0..3} of token lr -> 4
// CONSECUTIVE hidden elems. Hs is [16 tok][64 h] written with 4 packed
// bf16x4 (8B) stores per chunk instead of 16 scalar b16 column writes.
// XOR key (lr&7)<<1 keeps granule bit0 -> 16B-aligned fc2 reads.
// LN2 fused into the A-fragment build (mlp reads each row exactly ONCE ->
// fusion is free, unlike LN1->qkv).
// ---------------------------------------------------------------------------
__global__ __launch_bounds__(512, 4) void mlp_fused(
    const bf16* __restrict__ X1,    // [NTOK,192] bf16 (attn residual sum)
    const float* __restrict__ g2,   // norm2 gamma [192]
    const float* __restrict__ bt2,  // norm2 beta  [192]
    const bf16* __restrict__ W1b,   // [768,192] pre-swizzled
    const bf16* __restrict__ W2b,   // [12][192][64] pre-swizzled
    const float* __restrict__ b1,   // [768]
    const float* __restrict__ b2,   // [192]
    float* __restrict__ out) {      // [NTOK,192] f32
  __shared__ alignas(16) bf16 W1s[64 * 192];     // 24 KiB
  __shared__ alignas(16) bf16 W2s[192 * 64];     // 24 KiB
  __shared__ alignas(16) bf16 Hs[8][16 * 64];    // 16 KiB, wave-private slices
  __shared__ float Gs[192], Bn[192];             // 1.5 KiB LN params

  const int tid = threadIdx.x;
  const int lane = tid & 63;
  const int wave = tid >> 6;
  const int lr = lane & 15;
  const int quad = lane >> 4;
  const int m0 = blockIdx.x * 128;
  const int arow = m0 + wave * 16 + lr;          // this lane's A row

  if (tid < 192) { Gs[tid] = g2[tid]; Bn[tid] = bt2[tid]; }
  __syncthreads();

  // Load X1 rows + fused LN2 -> A fragments (bf16) in registers.
  bf16x8 xr[6];
  {
    const bf16* xp = X1 + (size_t)arow * CDIM + quad * 8;
#pragma unroll
    for (int ks = 0; ks < 6; ks++) xr[ks] = *(const bf16x8*)(xp + ks * 32);
  }
  float s1 = 0.f, s2 = 0.f;
#pragma unroll
  for (int ks = 0; ks < 6; ks++)
#pragma unroll
    for (int j = 0; j < 8; j++) {
      float v = (float)xr[ks][j];
      s1 += v;
      s2 = fmaf(v, v, s2);
    }
  s1 += __shfl_xor(s1, 16, 64); s1 += __shfl_xor(s1, 32, 64);
  s2 += __shfl_xor(s2, 16, 64); s2 += __shfl_xor(s2, 32, 64);
  float mean = s1 * (1.0f / 192.0f);
  float var = fmaxf(s2 * (1.0f / 192.0f) - mean * mean, 0.0f);
  float rstd = rsqrtf(var + 1e-5f);
  bf16x8 aF[6];
#pragma unroll
  for (int ks = 0; ks < 6; ks++) {
    int cb = ks * 32 + quad * 8;
    bf16x8 a;
#pragma unroll
    for (int j = 0; j < 8; j++)
      a[j] = (bf16)(((float)xr[ks][j] - mean) * rstd * Gs[cb + j] + Bn[cb + j]);
    aF[ks] = a;
  }

  f32x4 oacc[12];
#pragma unroll
  for (int nt = 0; nt < 12; nt++) oacc[nt] = (f32x4){0.f, 0.f, 0.f, 0.f};

  for (int c = 0; c < 12; c++) {
    const int h0 = c * 64;
    // stage W1 + W2 chunks via global_load_lds: 3+3 issues of 16B/lane.
    {
      const size_t cb = (size_t)c * 24576;       // chunk stride in bytes
      const int off = wave * 1024 + lane * 16;
      const char* gp1 = (const char*)W1b + cb + off;
      const char* gp2 = (const char*)W2b + cb + off;
      char* l1 = (char*)W1s + wave * 1024;
      char* l2 = (char*)W2s + wave * 1024;
#pragma unroll
      for (int i = 0; i < 3; i++) {
        __builtin_amdgcn_global_load_lds((gchar*)(gp1 + i * 8192),
                                         (lchar*)(l1 + i * 8192), 16, 0, 0);
        __builtin_amdgcn_global_load_lds((gchar*)(gp2 + i * 8192),
                                         (lchar*)(l2 + i * 8192), 16, 0, 0);
      }
    }
    __syncthreads();   // W1s/W2s ready

    // fc1 (swapped): hacc[hj][r] = H^T[h = hj*16+quad*4+r][t = lr]
    f32x4 hacc[4];
#pragma unroll
    for (int hj = 0; hj < 4; hj++) hacc[hj] = (f32x4){0.f, 0.f, 0.f, 0.f};
#pragma unroll
    for (int ks = 0; ks < 6; ks++) {
      int c8 = ks * 4 + quad;
      int base = (c8 & ~7) | ((c8 & 7) ^ (lr & 7));
#pragma unroll
      for (int hj = 0; hj < 4; hj++) {
        bf16x8 wf = *(const bf16x8*)(&W1s[(hj * 16 + lr) * 192 + base * 8]);
        hacc[hj] = __builtin_amdgcn_mfma_f32_16x16x32_bf16(wf, aF[ks], hacc[hj], 0, 0, 0);
      }
    }

    // bias + gelu (A&S 7.1.26 erf) -> packed transposed write: Hs[t][h],
    // 4 consecutive h per (hj) -> one bf16x4 (8B) store.
#pragma unroll
    for (int hj = 0; hj < 4; hj++) {
      float4 bh4 = *(const float4*)(&b1[h0 + hj * 16 + quad * 4]);
      float bhv[4] = {bh4.x, bh4.y, bh4.z, bh4.w};
      bf16x4 pk;
#pragma unroll
      for (int r = 0; r < 4; r++) {
        float h = hacc[hj][r] + bhv[r];
        float x = fabsf(h) * 0.70710678118654752f;
        float t = __fdividef(1.0f, fmaf(0.3275911f, x, 1.0f));
        float p = t * (0.254829592f +
                  t * (-0.284496736f +
                  t * (1.421413741f +
                  t * (-1.453152027f + t * 1.061405429f))));
        float er = fmaf(-p, __expf(-x * x), 1.0f);   // erf(|h|/sqrt2)
        er = copysignf(er, h);
        pk[r] = (bf16)(0.5f * h * (1.0f + er));
      }
      int gw = (hj * 4 + quad) ^ ((lr & 7) << 1);
      *(bf16x4*)(&Hs[wave][lr * 64 + gw * 4]) = pk;
    }
    // no __syncthreads: Hs[wave] is wave-private (lgkmcnt orders the hazard).

    // fc2: oacc[16x192] += H[16x64] @ W2chunk[192x64]^T
#pragma unroll
    for (int ks = 0; ks < 2; ks++) {
      int gr = (ks * 8 + quad * 2) ^ ((lr & 7) << 1);
      bf16x8 hF = *(const bf16x8*)(&Hs[wave][lr * 64 + gr * 4]);
      int c8 = ks * 4 + quad;
      int c8s = c8 ^ (lr & 7);
#pragma unroll
      for (int nt = 0; nt < 12; nt++) {
        bf16x8 wF = *(const bf16x8*)(&W2s[(nt * 16 + lr) * 64 + c8s * 8]);
        oacc[nt] = __builtin_amdgcn_mfma_f32_16x16x32_bf16(hF, wF, oacc[nt], 0, 0, 0);
      }
    }
    __syncthreads();   // W1s/W2s consumed; safe to restage next chunk
  }

  // epilogue: + fc2_b + residual x1, store f32.
#pragma unroll
  for (int nt = 0; nt < 12; nt++) {
    float fb = b2[nt * 16 + lr];
#pragma unroll
    for (int r = 0; r < 4; r++) {
      size_t row = (size_t)(m0 + wave * 16 + quad * 4 + r);
      size_t idx = row * CDIM + nt * 16 + lr;
      out[idx] = oacc[nt][r] + fb + (float)X1[idx];
    }
  }
}

// ---------------------------------------------------------------------------
// Workspace (peak ~192 MiB):
//   phase 1: Q [0, 150,994,944)  qkv ; T [150,994,944, 201,326,592) xw/attn
//   phase 2: X1 [0, 50,331,648) ; W1b/W2b at [52,428,800, +589,824)
// ---------------------------------------------------------------------------
extern "C" void kernel_launch(void* const* d_in, const int* in_sizes, int n_in,
                              void* d_out, int out_size, void* d_ws, size_t ws_size,
                              hipStream_t stream) {
  const float* x      = (const float*)d_in[0];
  const float* n1g    = (const float*)d_in[3];
  const float* n1b    = (const float*)d_in[4];
  const float* qkv_w  = (const float*)d_in[5];
  const float* qkv_b  = (const float*)d_in[6];
  const float* rpb    = (const float*)d_in[7];
  const float* proj_w = (const float*)d_in[8];
  const float* proj_b = (const float*)d_in[9];
  const float* n2g    = (const float*)d_in[10];
  const float* n2b    = (const float*)d_in[11];
  const float* fc1_w  = (const float*)d_in[12];
  const float* fc1_b  = (const float*)d_in[13];
  const float* fc2_w  = (const float*)d_in[14];
  const float* fc2_b  = (const float*)d_in[15];
  float* out = (float*)d_out;

  char* wsb = (char*)d_ws;
  bf16* Q   = (bf16*)wsb;                        // phase 1: qkv 151 MB
  bf16* X1  = (bf16*)wsb;                        // phase 2: x1 50 MB
  bf16* W1b = (bf16*)(wsb + 52428800ull);        // 294,912 B
  bf16* W2b = (bf16*)(wsb + 52428800ull + 294912ull);
  bf16* T   = (bf16*)(wsb + 150994944ull);       // xw -> attn out

  // 1. LN1 + shift + window partition: x -> T (xw)
  ln_kernel<true, float><<<32768, 256, 0, stream>>>(x, n1g, n1b, T);
  // 2. qkv = xw @ qkv_w^T + qkv_b : T -> Q   (XCD-swizzled)
  gemm_bt<0, float, bf16><<<dim3(9, 1024), 256, 0, stream>>>(
      T, qkv_w, qkv_b, nullptr, Q, NTOK, QKVC, CDIM, CDIM);
  // 3. windowed attention: Q -> T
  attn_kernel<<<dim3(2048, 6), 64, 0, stream>>>(Q, rpb, T);
  // 4. proj + window reverse + roll + residual(x): T -> X1 (Q dead)
  gemm_bt<3, float, bf16><<<dim3(3, 1024), 256, 0, stream>>>(
      T, proj_w, proj_b, x, X1, NTOK, CDIM, CDIM, CDIM);
  // 4b. weight conversion (region freed by Q)
  wconv_kernel<<<576, 256, 0, stream>>>(fc1_w, fc2_w, W1b, W2b);
  // 5. fused LN2 + MLP + residual -> out (128 tokens/block, 8 waves)
  mlp_fused<<<1024, 512, 0, stream>>>(X1, n2g, n2b, W1b, W2b, fc1_b, fc2_b, out);
}

// Round 8
// 524.091 us; speedup vs baseline: 1.2455x; 1.0338x over previous
//
#include <hip/hip_runtime.h>
#include <hip/hip_bf16.h>
#include <math.h>

typedef __bf16 bf16;
typedef __bf16 bf16x4 __attribute__((ext_vector_type(4)));
typedef __bf16 bf16x8 __attribute__((ext_vector_type(8)));
typedef float f32x4 __attribute__((ext_vector_type(4)));

typedef const __attribute__((address_space(1))) char gchar;
typedef __attribute__((address_space(3))) char lchar;

// Problem constants (B=32, H=W=64, C=192, WS=8, SHIFT=4, NH=6, hd=32)
#define BATCH 32
#define HW 64
#define L 4096
#define CDIM 192
#define NHEADS 6
#define HD 32
#define NTOK 131072          // B * L
#define QKVC 576             // 3*C
#define CH 768               // 4*C

// window-order token row -> source row in [B, 64, 64] layout (shift -4,-4
// fused): row = win*64 + n.
__device__ __forceinline__ int srcrow_of(int row) {
  int win = row >> 6, n = row & 63;
  int bb = win >> 6, wid = win & 63;
  int i = ((wid >> 3) << 3) + (n >> 3);
  int j = ((wid & 7) << 3) + (n & 7);
  return bb * L + ((i + 4) & 63) * HW + ((j + 4) & 63);
}

// ---------------------------------------------------------------------------
// LayerNorm pass (LN1). PERM=true fuses cyclic shift (-4,-4) + window
// partition into the store order. One wave per token.
// (round-6 lesson: keep LN1 separate; fusing into qkv duplicates LN x9.)
// ---------------------------------------------------------------------------
template <bool PERM, typename TIN>
__global__ __launch_bounds__(256) void ln_kernel(const TIN* __restrict__ xin,
                                                 const float* __restrict__ g,
                                                 const float* __restrict__ bta,
                                                 bf16* __restrict__ yout) {
  int wave = threadIdx.x >> 6;
  int lane = threadIdx.x & 63;
  int tok = blockIdx.x * 4 + wave;
  int src = PERM ? srcrow_of(tok) : tok;
  const TIN* sp = xin + (size_t)src * CDIM;
  float v0 = (float)sp[lane];
  float v1 = (float)sp[lane + 64];
  float v2 = (float)sp[lane + 128];
  float s = v0 + v1 + v2;
#pragma unroll
  for (int off = 32; off; off >>= 1) s += __shfl_xor(s, off, 64);
  float mean = s * (1.0f / 192.0f);
  float d0 = v0 - mean, d1 = v1 - mean, d2 = v2 - mean;
  float q = d0 * d0 + d1 * d1 + d2 * d2;
#pragma unroll
  for (int off = 32; off; off >>= 1) q += __shfl_xor(q, off, 64);
  float rstd = rsqrtf(q * (1.0f / 192.0f) + 1e-5f);
  bf16* dp = yout + (size_t)tok * CDIM;
  dp[lane]       = (bf16)(d0 * rstd * g[lane]       + bta[lane]);
  dp[lane + 64]  = (bf16)(d1 * rstd * g[lane + 64]  + bta[lane + 64]);
  dp[lane + 128] = (bf16)(d2 * rstd * g[lane + 128] + bta[lane + 128]);
}

// ---------------------------------------------------------------------------
// GEMM: C[M,N] = A[M,K] @ W[N,K]^T + bias. A bf16, W f32 (converted while
// staging). BM=128 BN=64 BK=32, 4 waves, XCD-swizzled grid (T1, bijective
// since nb%8==0).
// EPI 0: +bias. 3: +bias + window-reverse + roll(+4,+4) + residual res (f32)
// written at permuted location.
// ---------------------------------------------------------------------------
template <int EPI, typename TR, typename TO>
__global__ __launch_bounds__(256) void gemm_bt(const bf16* __restrict__ A,
                                               const float* __restrict__ W,
                                               const float* __restrict__ bias,
                                               const TR* __restrict__ res,
                                               TO* __restrict__ Cout,
                                               int M, int N, int K, int ldw) {
  __shared__ alignas(16) bf16 As[128 * 32];
  __shared__ alignas(16) bf16 Bs[64 * 32];
  const int gx = gridDim.x;
  const int nb = gx * gridDim.y;
  const int id = blockIdx.y * gx + blockIdx.x;
  const int per = nb >> 3;
  const int jj = ((id & 7) * per) + (id >> 3);   // nb % 8 == 0 guaranteed
  const int n0 = (jj % gx) * 64;
  const int m0 = (jj / gx) * 128;
  const int tid = threadIdx.x;
  const int lane = tid & 63;
  const int wave = tid >> 6;
  const int wm = (wave >> 1) * 64;
  const int wn = (wave & 1) * 32;
  const int lr = lane & 15;
  const int quad = lane >> 4;

  f32x4 acc[4][2];
#pragma unroll
  for (int i = 0; i < 4; i++)
#pragma unroll
    for (int j = 0; j < 2; j++) acc[i][j] = (f32x4){0.f, 0.f, 0.f, 0.f};

  const int arow = tid >> 2;        // 0..63
  const int akq = (tid & 3) * 8;    // 0,8,16,24

  for (int k0 = 0; k0 < K; k0 += 32) {
    const bf16* Ap = A + (size_t)(m0 + arow) * K + k0 + akq;
    *(uint4*)(&As[arow * 32 + akq]) = *(const uint4*)Ap;
    *(uint4*)(&As[(arow + 64) * 32 + akq]) = *(const uint4*)(Ap + (size_t)64 * K);
    const float* Wp = W + (size_t)(n0 + arow) * ldw + k0 + akq;
    float4 w0 = *(const float4*)Wp;
    float4 w1 = *(const float4*)(Wp + 4);
    bf16x8 bw;
    bw[0] = (bf16)w0.x; bw[1] = (bf16)w0.y; bw[2] = (bf16)w0.z; bw[3] = (bf16)w0.w;
    bw[4] = (bf16)w1.x; bw[5] = (bf16)w1.y; bw[6] = (bf16)w1.z; bw[7] = (bf16)w1.w;
    *(bf16x8*)(&Bs[arow * 32 + akq]) = bw;
    __syncthreads();

    bf16x8 af[4], bfr[2];
#pragma unroll
    for (int mi = 0; mi < 4; mi++)
      af[mi] = *(const bf16x8*)(&As[(wm + mi * 16 + lr) * 32 + quad * 8]);
#pragma unroll
    for (int nj = 0; nj < 2; nj++)
      bfr[nj] = *(const bf16x8*)(&Bs[(wn + nj * 16 + lr) * 32 + quad * 8]);
#pragma unroll
    for (int mi = 0; mi < 4; mi++)
#pragma unroll
      for (int nj = 0; nj < 2; nj++)
        acc[mi][nj] = __builtin_amdgcn_mfma_f32_16x16x32_bf16(af[mi], bfr[nj],
                                                              acc[mi][nj], 0, 0, 0);
    __syncthreads();
  }

#pragma unroll
  for (int mi = 0; mi < 4; mi++) {
#pragma unroll
    for (int nj = 0; nj < 2; nj++) {
      int col = n0 + wn + nj * 16 + lr;
      float bv = bias[col];
#pragma unroll
      for (int r = 0; r < 4; r++) {
        int row = m0 + wm + mi * 16 + quad * 4 + r;
        float v = acc[mi][nj][r] + bv;
        size_t didx;
        if (EPI == 3) {
          didx = ((size_t)srcrow_of(row)) * (size_t)N + col;
          v += (float)res[didx];
        } else {
          didx = (size_t)row * N + col;
        }
        Cout[didx] = (TO)v;
      }
    }
  }
}

// ---------------------------------------------------------------------------
// Attention: one wave per (window, head). grid = (2048, 6), block = 64.
// LDS overlay: Ps reuses Qs+Ks (single wave -> DS ops program-ordered).
// 12.3KB/block -> 13 blocks/CU.
// ---------------------------------------------------------------------------
__device__ __forceinline__ int region64(int h) {
  return (h < 56) ? 0 : ((h < 60) ? 1 : 2);
}

__global__ __launch_bounds__(64) void attn_kernel(const bf16* __restrict__ qkv,
                                                  const float* __restrict__ rpb,
                                                  bf16* __restrict__ out) {
  __shared__ alignas(16) bf16 QKP[64 * 64];   // Qs | Ks, later reused as Ps
  __shared__ alignas(16) bf16 Vt[32 * 64];
  bf16* Qs = QKP;
  bf16* Ks = QKP + 64 * 32;
  bf16* Ps = QKP;
  const int win = blockIdx.x;
  const int head = blockIdx.y;
  const int lane = threadIdx.x;
  const int lr = lane & 15;
  const int quad = lane >> 4;
  const int wid = win & 63;
  const int wi = wid >> 3, wj = wid & 7;

  const bf16* base = qkv + (size_t)win * 64 * QKVC + head * HD;
#pragma unroll
  for (int rep = 0; rep < 4; rep++) {
    int r = (lane >> 2) + rep * 16;
    int c = (lane & 3) * 8;
    *(uint4*)(&Qs[r * 32 + c]) = *(const uint4*)(base + (size_t)r * QKVC + c);
    *(uint4*)(&Ks[r * 32 + c]) = *(const uint4*)(base + CDIM + (size_t)r * QKVC + c);
    uint4 vv = *(const uint4*)(base + 2 * CDIM + (size_t)r * QKVC + c);
    bf16x8 v8 = __builtin_bit_cast(bf16x8, vv);
#pragma unroll
    for (int j = 0; j < 8; j++) Vt[(c + j) * 64 + r] = v8[j];
  }
  __syncthreads();

  f32x4 s[4][4];
  {
    bf16x8 qf[4], kf[4];
#pragma unroll
    for (int mi = 0; mi < 4; mi++)
      qf[mi] = *(const bf16x8*)(&Qs[(mi * 16 + lr) * 32 + quad * 8]);
#pragma unroll
    for (int nj = 0; nj < 4; nj++)
      kf[nj] = *(const bf16x8*)(&Ks[(nj * 16 + lr) * 32 + quad * 8]);
#pragma unroll
    for (int mi = 0; mi < 4; mi++)
#pragma unroll
      for (int nj = 0; nj < 4; nj++)
        s[mi][nj] = __builtin_amdgcn_mfma_f32_16x16x32_bf16(
            qf[mi], kf[nj], (f32x4){0.f, 0.f, 0.f, 0.f}, 0, 0, 0);
  }

  const float scale = 0.17677669529663687f;
#pragma unroll
  for (int mi = 0; mi < 4; mi++) {
#pragma unroll
    for (int nj = 0; nj < 4; nj++) {
#pragma unroll
      for (int r = 0; r < 4; r++) {
        int rr = mi * 16 + quad * 4 + r;
        int cc = nj * 16 + lr;
        int qi = rr >> 3, qj = rr & 7, ki = cc >> 3, kj = cc & 7;
        int idx = (qi - ki + 7) * 15 + (qj - kj + 7);
        float bv = rpb[idx * NHEADS + head];
        int regr = 3 * region64(wi * 8 + qi) + region64(wj * 8 + qj);
        int regc = 3 * region64(wi * 8 + ki) + region64(wj * 8 + kj);
        float mv = (regr != regc) ? -100.0f : 0.0f;
        s[mi][nj][r] = s[mi][nj][r] * scale + bv + mv;
      }
    }
  }

#pragma unroll
  for (int mi = 0; mi < 4; mi++) {
#pragma unroll
    for (int r = 0; r < 4; r++) {
      float mx = s[mi][0][r];
#pragma unroll
      for (int nj = 1; nj < 4; nj++) mx = fmaxf(mx, s[mi][nj][r]);
#pragma unroll
      for (int off = 1; off < 16; off <<= 1) mx = fmaxf(mx, __shfl_xor(mx, off, 64));
      float sum = 0.f;
#pragma unroll
      for (int nj = 0; nj < 4; nj++) {
        float p = __expf(s[mi][nj][r] - mx);
        s[mi][nj][r] = p;
        sum += p;
      }
#pragma unroll
      for (int off = 1; off < 16; off <<= 1) sum += __shfl_xor(sum, off, 64);
      float inv = 1.0f / sum;
#pragma unroll
      for (int nj = 0; nj < 4; nj++) s[mi][nj][r] *= inv;
    }
  }

#pragma unroll
  for (int mi = 0; mi < 4; mi++)
#pragma unroll
    for (int nj = 0; nj < 4; nj++)
#pragma unroll
      for (int r = 0; r < 4; r++)
        Ps[(mi * 16 + quad * 4 + r) * 64 + nj * 16 + lr] = (bf16)s[mi][nj][r];
  __syncthreads();

  f32x4 o[4][2];
#pragma unroll
  for (int mi = 0; mi < 4; mi++)
#pragma unroll
    for (int nj = 0; nj < 2; nj++) o[mi][nj] = (f32x4){0.f, 0.f, 0.f, 0.f};
#pragma unroll
  for (int ks = 0; ks < 2; ks++) {
    bf16x8 pf[4], vf[2];
#pragma unroll
    for (int mi = 0; mi < 4; mi++)
      pf[mi] = *(const bf16x8*)(&Ps[(mi * 16 + lr) * 64 + ks * 32 + quad * 8]);
#pragma unroll
    for (int nj = 0; nj < 2; nj++)
      vf[nj] = *(const bf16x8*)(&Vt[(nj * 16 + lr) * 64 + ks * 32 + quad * 8]);
#pragma unroll
    for (int mi = 0; mi < 4; mi++)
#pragma unroll
      for (int nj = 0; nj < 2; nj++)
        o[mi][nj] = __builtin_amdgcn_mfma_f32_16x16x32_bf16(pf[mi], vf[nj],
                                                            o[mi][nj], 0, 0, 0);
  }

#pragma unroll
  for (int mi = 0; mi < 4; mi++)
#pragma unroll
    for (int nj = 0; nj < 2; nj++)
#pragma unroll
      for (int r = 0; r < 4; r++) {
        size_t row = (size_t)win * 64 + mi * 16 + quad * 4 + r;
        int col = head * HD + nj * 16 + lr;
        out[row * CDIM + col] = (bf16)o[mi][nj][r];
      }
}

// ---------------------------------------------------------------------------
// Weight pre-conversion, PRE-SWIZZLED for linear global_load_lds staging.
//   W1b[h*192 + gs*8 + e]          = fc1_w[h*192 + g*8 + e],
//       g = (gs & ~7) | ((gs & 7) ^ (h & 7))            [8x 16B granules]
//   W2b: [24 chunks][192 n][32 k], 4x 16B granules per row, key (n>>1)&3:
//   W2b[c*6144 + n*32 + p*8 + e]   = fc2_w[n*768 + c*32 + g*8 + e],
//       g = p ^ ((n>>1)&3)
// ---------------------------------------------------------------------------
__global__ __launch_bounds__(256) void wconv_kernel(const float* __restrict__ fc1w,
                                                    const float* __restrict__ fc2w,
                                                    bf16* __restrict__ W1b,
                                                    bf16* __restrict__ W2b) {
  int i = blockIdx.x * 256 + threadIdx.x;   // 0..147455
  {
    int h = i / 192;
    int cc = i - h * 192;
    int gs = cc >> 3, e = cc & 7;
    int g = (gs & ~7) | ((gs & 7) ^ (h & 7));
    W1b[i] = (bf16)fc1w[h * 192 + g * 8 + e];
  }
  {
    int c = i / 6144;          // chunk 0..23
    int rem = i - c * 6144;
    int n = rem >> 5;          // 0..191
    int cc = rem & 31;
    int p = cc >> 3;           // physical granule 0..3
    int e = cc & 7;
    int g = p ^ ((n >> 1) & 3);
    W2b[i] = (bf16)fc2w[n * 768 + c * 32 + g * 8 + e];
  }
}

// ---------------------------------------------------------------------------
// Fused LN2 + MLP v5: out = x1 + fc2_b + gelu(LN(x1)@fc1^T + b1)@fc2^T.
// Wave-owned-rows (128 tokens / 8 waves / block, 16 rows/wave).
// NEW vs v4 (which was neutral: VALU cut didn't move time -> stall-bound):
// 2-PHASE DOUBLE-BUFFERED weight staging (T3-minimum). Chunks halved to
// 32 H (24 chunks); W1/W2 double-buffered (4 x 12 KiB). STAGE(c+1, buf^1)
// issues BEFORE compute(c), so the ~200-400cy L2 load latency lands under
// the compute phase instead of at an immediate barrier drain. LDS = 58.9 KiB
// -> still 2 blocks/CU (occupancy preserved).
// Staging split: waves 0-3 load W1 chunk, waves 4-7 load W2 chunk (3 x 16B
// global_load_lds each, linear dest, swizzle pre-baked in global).
// Hs per wave = [16 tok][32 h], 8B-granule XOR key (lr&6): fc2's 16B hF read
// stays contiguous (key bit0=0), reads 2-way bank-spread (free).
// ---------------------------------------------------------------------------
__global__ __launch_bounds__(512, 4) void mlp_fused(
    const bf16* __restrict__ X1,    // [NTOK,192] bf16 (attn residual sum)
    const float* __restrict__ g2,   // norm2 gamma [192]
    const float* __restrict__ bt2,  // norm2 beta  [192]
    const bf16* __restrict__ W1b,   // [768,192] pre-swizzled
    const bf16* __restrict__ W2b,   // [24][192][32] pre-swizzled
    const float* __restrict__ b1,   // [768]
    const float* __restrict__ b2,   // [192]
    float* __restrict__ out) {      // [NTOK,192] f32
  __shared__ alignas(16) bf16 W1s[2][32 * 192];  // 2 x 12 KiB
  __shared__ alignas(16) bf16 W2s[2][192 * 32];  // 2 x 12 KiB
  __shared__ alignas(16) bf16 Hs[8][16 * 32];    // 8 KiB, wave-private slices
  __shared__ float Gs[192], Bn[192];             // 1.5 KiB LN params

  const int tid = threadIdx.x;
  const int lane = tid & 63;
  const int wave = tid >> 6;
  const int lr = lane & 15;
  const int quad = lane >> 4;
  const int m0 = blockIdx.x * 128;
  const int arow = m0 + wave * 16 + lr;          // this lane's A row

  // stage chunk c (32 H rows of W1 = 12,288 B; [192][32] W2 = 12,288 B)
  // into buffer b. Waves 0-3: W1; waves 4-7: W2. 3 x 1024 B per wave.
  auto stage = [&](int c, int b) {
    const int off = (wave & 3) * 3072 + lane * 16;
    if (wave < 4) {
      const char* gp = (const char*)W1b + (size_t)c * 12288 + off;
      char* lp = (char*)(&W1s[b][0]) + off;
#pragma unroll
      for (int i = 0; i < 3; i++)
        __builtin_amdgcn_global_load_lds((gchar*)(gp + i * 1024),
                                         (lchar*)(lp + i * 1024), 16, 0, 0);
    } else {
      const char* gp = (const char*)W2b + (size_t)c * 12288 + off;
      char* lp = (char*)(&W2s[b][0]) + off;
#pragma unroll
      for (int i = 0; i < 3; i++)
        __builtin_amdgcn_global_load_lds((gchar*)(gp + i * 1024),
                                         (lchar*)(lp + i * 1024), 16, 0, 0);
    }
  };

  if (tid < 192) { Gs[tid] = g2[tid]; Bn[tid] = bt2[tid]; }
  stage(0, 0);                 // chunk 0 loads fly under the LN2 prologue
  __syncthreads();             // Gs/Bn visible AND chunk-0 staged (vmcnt drain)

  // Load X1 rows + fused LN2 -> A fragments (bf16) in registers.
  bf16x8 xr[6];
  {
    const bf16* xp = X1 + (size_t)arow * CDIM + quad * 8;
#pragma unroll
    for (int ks = 0; ks < 6; ks++) xr[ks] = *(const bf16x8*)(xp + ks * 32);
  }
  float s1 = 0.f, s2 = 0.f;
#pragma unroll
  for (int ks = 0; ks < 6; ks++)
#pragma unroll
    for (int j = 0; j < 8; j++) {
      float v = (float)xr[ks][j];
      s1 += v;
      s2 = fmaf(v, v, s2);
    }
  s1 += __shfl_xor(s1, 16, 64); s1 += __shfl_xor(s1, 32, 64);
  s2 += __shfl_xor(s2, 16, 64); s2 += __shfl_xor(s2, 32, 64);
  float mean = s1 * (1.0f / 192.0f);
  float var = fmaxf(s2 * (1.0f / 192.0f) - mean * mean, 0.0f);
  float rstd = rsqrtf(var + 1e-5f);
  bf16x8 aF[6];
#pragma unroll
  for (int ks = 0; ks < 6; ks++) {
    int cb = ks * 32 + quad * 8;
    bf16x8 a;
#pragma unroll
    for (int j = 0; j < 8; j++)
      a[j] = (bf16)(((float)xr[ks][j] - mean) * rstd * Gs[cb + j] + Bn[cb + j]);
    aF[ks] = a;
  }

  f32x4 oacc[12];
#pragma unroll
  for (int nt = 0; nt < 12; nt++) oacc[nt] = (f32x4){0.f, 0.f, 0.f, 0.f};

  int cur = 0;
  for (int c = 0; c < 24; c++) {
    if (c < 23) stage(c + 1, cur ^ 1);   // async: lands during compute below
    const int h0 = c * 32;

    // fc1 (swapped): hacc[hj][r] = H^T[h = hj*16+quad*4+r][t = lr]
    f32x4 hacc[2];
    hacc[0] = (f32x4){0.f, 0.f, 0.f, 0.f};
    hacc[1] = (f32x4){0.f, 0.f, 0.f, 0.f};
#pragma unroll
    for (int ks = 0; ks < 6; ks++) {
      int c8 = ks * 4 + quad;
      int base = (c8 & ~7) | ((c8 & 7) ^ (lr & 7));
#pragma unroll
      for (int hj = 0; hj < 2; hj++) {
        bf16x8 wf = *(const bf16x8*)(&W1s[cur][(hj * 16 + lr) * 192 + base * 8]);
        hacc[hj] = __builtin_amdgcn_mfma_f32_16x16x32_bf16(wf, aF[ks], hacc[hj], 0, 0, 0);
      }
    }

    // bias + gelu (A&S 7.1.26 erf) -> Hs[t][h], packed bf16x4, key lr&6.
#pragma unroll
    for (int hj = 0; hj < 2; hj++) {
      float4 bh4 = *(const float4*)(&b1[h0 + hj * 16 + quad * 4]);
      float bhv[4] = {bh4.x, bh4.y, bh4.z, bh4.w};
      bf16x4 pk;
#pragma unroll
      for (int r = 0; r < 4; r++) {
        float h = hacc[hj][r] + bhv[r];
        float x = fabsf(h) * 0.70710678118654752f;
        float t = __fdividef(1.0f, fmaf(0.3275911f, x, 1.0f));
        float p = t * (0.254829592f +
                  t * (-0.284496736f +
                  t * (1.421413741f +
                  t * (-1.453152027f + t * 1.061405429f))));
        float er = fmaf(-p, __expf(-x * x), 1.0f);   // erf(|h|/sqrt2)
        er = copysignf(er, h);
        pk[r] = (bf16)(0.5f * h * (1.0f + er));
      }
      int g = hj * 4 + quad;            // logical 8B-granule (4 h-elems)
      int p8 = g ^ (lr & 6);            // physical granule
      *(bf16x4*)(&Hs[wave][lr * 32 + p8 * 4]) = pk;
    }
    // no __syncthreads: Hs[wave] is wave-private (lgkmcnt orders the hazard).

    // fc2: oacc[16 tok x 192] += H[16x32] @ W2chunk[192x32]^T  (one k-step)
    {
      int p2 = (quad * 2) ^ (lr & 6);   // even -> 16B-contiguous pair
      bf16x8 hF = *(const bf16x8*)(&Hs[wave][lr * 32 + p2 * 4]);
      int key = (lr >> 1) & 3;
#pragma unroll
      for (int nt = 0; nt < 12; nt++) {
        int p = quad ^ key;
        bf16x8 wF = *(const bf16x8*)(&W2s[cur][(nt * 16 + lr) * 32 + p * 8]);
        oacc[nt] = __builtin_amdgcn_mfma_f32_16x16x32_bf16(hF, wF, oacc[nt], 0, 0, 0);
      }
    }
    __syncthreads();   // drains vmcnt: next chunk staged; buf[cur] consumed
    cur ^= 1;
  }

  // epilogue: + fc2_b + residual x1, store f32.
#pragma unroll
  for (int nt = 0; nt < 12; nt++) {
    float fb = b2[nt * 16 + lr];
#pragma unroll
    for (int r = 0; r < 4; r++) {
      size_t row = (size_t)(m0 + wave * 16 + quad * 4 + r);
      size_t idx = row * CDIM + nt * 16 + lr;
      out[idx] = oacc[nt][r] + fb + (float)X1[idx];
    }
  }
}

// ---------------------------------------------------------------------------
// Workspace (peak ~192 MiB):
//   phase 1: Q [0, 150,994,944)  qkv ; T [150,994,944, 201,326,592) xw/attn
//   phase 2: X1 [0, 50,331,648) ; W1b/W2b at [52,428,800, +589,824)
// ---------------------------------------------------------------------------
extern "C" void kernel_launch(void* const* d_in, const int* in_sizes, int n_in,
                              void* d_out, int out_size, void* d_ws, size_t ws_size,
                              hipStream_t stream) {
  const float* x      = (const float*)d_in[0];
  const float* n1g    = (const float*)d_in[3];
  const float* n1b    = (const float*)d_in[4];
  const float* qkv_w  = (const float*)d_in[5];
  const float* qkv_b  = (const float*)d_in[6];
  const float* rpb    = (const float*)d_in[7];
  const float* proj_w = (const float*)d_in[8];
  const float* proj_b = (const float*)d_in[9];
  const float* n2g    = (const float*)d_in[10];
  const float* n2b    = (const float*)d_in[11];
  const float* fc1_w  = (const float*)d_in[12];
  const float* fc1_b  = (const float*)d_in[13];
  const float* fc2_w  = (const float*)d_in[14];
  const float* fc2_b  = (const float*)d_in[15];
  float* out = (float*)d_out;

  char* wsb = (char*)d_ws;
  bf16* Q   = (bf16*)wsb;                        // phase 1: qkv 151 MB
  bf16* X1  = (bf16*)wsb;                        // phase 2: x1 50 MB
  bf16* W1b = (bf16*)(wsb + 52428800ull);        // 294,912 B
  bf16* W2b = (bf16*)(wsb + 52428800ull + 294912ull);
  bf16* T   = (bf16*)(wsb + 150994944ull);       // xw -> attn out

  // 1. LN1 + shift + window partition: x -> T (xw)
  ln_kernel<true, float><<<32768, 256, 0, stream>>>(x, n1g, n1b, T);
  // 2. qkv = xw @ qkv_w^T + qkv_b : T -> Q   (XCD-swizzled)
  gemm_bt<0, float, bf16><<<dim3(9, 1024), 256, 0, stream>>>(
      T, qkv_w, qkv_b, nullptr, Q, NTOK, QKVC, CDIM, CDIM);
  // 3. windowed attention: Q -> T
  attn_kernel<<<dim3(2048, 6), 64, 0, stream>>>(Q, rpb, T);
  // 4. proj + window reverse + roll + residual(x): T -> X1 (Q dead)
  gemm_bt<3, float, bf16><<<dim3(3, 1024), 256, 0, stream>>>(
      T, proj_w, proj_b, x, X1, NTOK, CDIM, CDIM, CDIM);
  // 4b. weight conversion (region freed by Q)
  wconv_kernel<<<576, 256, 0, stream>>>(fc1_w, fc2_w, W1b, W2b);
  // 5. fused LN2 + MLP + residual -> out (128 tokens/block, 8 waves,
  //    2-phase double-buffered weight staging)
  mlp_fused<<<1024, 512, 0, stream>>>(X1, n2g, n2b, W1b, W2b, fc1_b, fc2_b, out);
}